// Round 6
// baseline (158.555 us; speedup 1.0000x reference)
//
#include <hip/hip_runtime.h>
#include <stdint.h>

// Problem constants (fixed by reference)
#define D_DIRS 1024
#define P_PTS  256
#define R_RANK 64
#define K_SUB  1024

typedef float v4f __attribute__((ext_vector_type(4)));

// ws layout (floats):
//   aP[1024][2][64]   @ 0        (131072)  -- per-(d,p-half) partial a
//   bP[1024][2][64]   @ 131072   (131072)
//   Mpart[32][64][64] @ 262144   (131072)
//   Msum[64][64]      @ 0        (4096)    -- overlaps aP, written after k2 read it
// total 1.5 MiB
#define WS_AP 0
#define WS_BP (D_DIRS * 2 * R_RANK)
#define WS_M  (2 * D_DIRS * 2 * R_RANK)
#define WS_MSUM 0
#define NB_B 32
#define DCHUNK (D_DIRS / NB_B) // 32

__device__ __forceinline__ v4f shfl_xor_v4(v4f v, int m) {
    v4f r;
    r.x = __shfl_xor(v.x, m);
    r.y = __shfl_xor(v.y, m);
    r.z = __shfl_xor(v.z, m);
    r.w = __shfl_xor(v.w, m);
    return r;
}

// Async global->LDS DMA, 16 B/lane: lane's 16 B from g+lane*16 lands at
// (wave-uniform) l + lane*16. [measured: learn_hip m97 emits global_load_lds_dwordx4]
__device__ __forceinline__ void load_lds_1k(const void* g, void* l) {
    __builtin_amdgcn_global_load_lds(
        (const __attribute__((address_space(1))) uint32_t*)g,
        (__attribute__((address_space(3))) uint32_t*)l, 16, 0, 0);
}

// ---------------------------------------------------------------------------
// Kernel 1: p-reduction via direct-to-LDS DMA streaming.
// R1-R5 post-mortem: every VGPR-return load structure (any TLP/MLP/stream
// shape/barrier count) plateaus at 3.0-3.6 TB/s read while writes stream at
// 6.6 TB/s -> per-CU L1 outstanding-line pool is the suspected cap
// (~88 lines/CU at ~400ns). global_load_lds bypasses the VGPR return path
// (no L1 allocation) - different tracking structure, the m93->m97 lever.
//
// 256 blocks x 512 threads. Wave w: d = 4*bid + (w>>1), p-half = w&1
// (p in [half*128, half*128+128), contiguous 32 KB per array).
// Wave-PRIVATE 2-deep LDS double buffer (no __syncthreads anywhere):
// 16 chunks of 2 KB per array; issue chunk c+1 (4 DMA instrs), then
// s_waitcnt vmcnt(4) (partial drain - chunk c landed, c+1 in flight),
// then 4x ds_read_b128 + adds. Lane l: rq = l&15 (float4 of r),
// pg = l>>4 reads chunk rows pg and pg+4. After 16 chunks shfl_xor 16/32
// folds pg; lanes 0..15 store the (d,half) partial row. k2 sums halves.
// LDS 64 KB/block -> 2 blocks/CU -> 16 waves/CU.
// ---------------------------------------------------------------------------
__global__ __launch_bounds__(512) void k_reduce_p(const float* __restrict__ atten,
                                                  const float* __restrict__ rad,
                                                  float* __restrict__ ws) {
    const int t    = threadIdx.x;
    const int wave = t >> 6;
    const int lane = t & 63;
    const int d    = blockIdx.x * 4 + (wave >> 1);
    const int half = wave & 1;
    const int rq   = lane & 15;
    const int pg   = lane >> 4;

    __shared__ char lds[8][2][2][2048]; // [wave][array][buf][bytes] = 64 KiB

    const char* gA = (const char*)(atten + (size_t)d * 16384 + half * 8192);
    const char* gB = (const char*)(rad   + (size_t)d * 16384 + half * 8192);
    const int lane16 = lane * 16;

    auto issue = [&](int c, int s) {
        const char* ga = gA + c * 2048 + lane16;
        const char* gb = gB + c * 2048 + lane16;
        load_lds_1k(ga,        &lds[wave][0][s][0]);
        load_lds_1k(ga + 1024, &lds[wave][0][s][1024]);
        load_lds_1k(gb,        &lds[wave][1][s][0]);
        load_lds_1k(gb + 1024, &lds[wave][1][s][1024]);
    };

    v4f acc_a = {0.f, 0.f, 0.f, 0.f};
    v4f acc_b = {0.f, 0.f, 0.f, 0.f};

    auto consume = [&](int s) {
        asm volatile("" ::: "memory"); // keep ds_reads below the waitcnt
        const float* bufA = (const float*)&lds[wave][0][s][0];
        const float* bufB = (const float*)&lds[wave][1][s][0];
        const v4f a0 = *(const v4f*)(bufA + pg * 64 + rq * 4);
        const v4f a1 = *(const v4f*)(bufA + (pg + 4) * 64 + rq * 4);
        const v4f b0 = *(const v4f*)(bufB + pg * 64 + rq * 4);
        const v4f b1 = *(const v4f*)(bufB + (pg + 4) * 64 + rq * 4);
        acc_a = acc_a + (a0 + a1);
        acc_b = acc_b + (b0 + b1);
        asm volatile("" ::: "memory"); // keep next issue() below these reads
    };

    issue(0, 0);
#pragma unroll
    for (int c = 0; c < 15; ++c) {
        issue(c + 1, (c + 1) & 1);
        __builtin_amdgcn_s_waitcnt(0x0F74); // vmcnt(4): chunk c landed, c+1 pending
        consume(c & 1);
    }
    __builtin_amdgcn_s_waitcnt(0x0F70);     // vmcnt(0): last chunk landed
    consume(15 & 1);

    // Fold pg groups (lanes sharing rq): xor 16, 32. No barriers.
    acc_a = acc_a + shfl_xor_v4(acc_a, 16);
    acc_a = acc_a + shfl_xor_v4(acc_a, 32);
    acc_b = acc_b + shfl_xor_v4(acc_b, 16);
    acc_b = acc_b + shfl_xor_v4(acc_b, 32);

    if (pg == 0) { // lanes 0..15, lane == rq
        ((v4f*)(ws + WS_AP))[d * 32 + half * 16 + rq] = acc_a;
        ((v4f*)(ws + WS_BP))[d * 32 + half * 16 + rq] = acc_b;
    }
}

// ---------------------------------------------------------------------------
// Kernel 2: partial M.  Block bb covers d in [bb*32, bb*32+32), all (r,r').
// Stage-in now sums the two p-half partials per d (k1 is barrier-free).
// ---------------------------------------------------------------------------
__global__ __launch_bounds__(256) void k_partial_m(float* __restrict__ ws) {
    const int bb = blockIdx.x;
    const int t  = threadIdx.x;

    __shared__ float sa[DCHUNK * R_RANK]; // 8 KiB
    __shared__ float sb[DCHUNK * R_RANK]; // 8 KiB

    const float4* aP = (const float4*)(ws + WS_AP) + bb * (DCHUNK * 32);
    const float4* bP = (const float4*)(ws + WS_BP) + bb * (DCHUNK * 32);
    float4* sa4 = (float4*)sa;
    float4* sb4 = (float4*)sb;
#pragma unroll
    for (int i = t; i < DCHUNK * 16; i += 256) {
        const int dd = i >> 4, q = i & 15;
        const float4 xa = aP[dd * 32 + q], ya = aP[dd * 32 + 16 + q];
        sa4[i] = make_float4(xa.x + ya.x, xa.y + ya.y, xa.z + ya.z, xa.w + ya.w);
        const float4 xb = bP[dd * 32 + q], yb = bP[dd * 32 + 16 + q];
        sb4[i] = make_float4(xb.x + yb.x, xb.y + yb.y, xb.z + yb.z, xb.w + yb.w);
    }
    __syncthreads();

    const int c  = t & 63;
    const int wg = t >> 6;

    float acc[16];
#pragma unroll
    for (int i = 0; i < 16; ++i) acc[i] = 0.f;

    for (int dd = 0; dd < DCHUNK; ++dd) {
        const float bv = sb[dd * 64 + c];
        const float4* ar = (const float4*)&sa[dd * 64 + wg * 16];
        const float4 a0 = ar[0], a1 = ar[1], a2 = ar[2], a3 = ar[3];
        acc[0]  += a0.x * bv; acc[1]  += a0.y * bv; acc[2]  += a0.z * bv; acc[3]  += a0.w * bv;
        acc[4]  += a1.x * bv; acc[5]  += a1.y * bv; acc[6]  += a1.z * bv; acc[7]  += a1.w * bv;
        acc[8]  += a2.x * bv; acc[9]  += a2.y * bv; acc[10] += a2.z * bv; acc[11] += a2.w * bv;
        acc[12] += a3.x * bv; acc[13] += a3.y * bv; acc[14] += a3.z * bv; acc[15] += a3.w * bv;
    }

    float* Mp = ws + WS_M + bb * 4096;
#pragma unroll
    for (int i = 0; i < 16; ++i) Mp[(wg * 16 + i) * 64 + c] = acc[i];
}

// ---------------------------------------------------------------------------
// Kernel 3: reduce the 32 partial Ms -> Msum (4096 floats @ ws[0]).
// ---------------------------------------------------------------------------
__global__ __launch_bounds__(256) void k_reduce_m(float* __restrict__ ws) {
    const int tg = blockIdx.x * 256 + threadIdx.x; // float4 column 0..1023
    const float4* Mp4 = (const float4*)(ws + WS_M);
    float4 s = make_float4(0.f, 0.f, 0.f, 0.f);
#pragma unroll
    for (int g = 0; g < NB_B; ++g) {
        const float4 v = Mp4[g * 1024 + tg];
        s.x += v.x; s.y += v.y; s.z += v.z; s.w += v.w;
    }
    ((float4*)(ws + WS_MSUM))[tg] = s;
}

// ---------------------------------------------------------------------------
// Kernel 4: csi[k] = (1/D) F[k] Msum F[k]^T.
// ---------------------------------------------------------------------------
__global__ __launch_bounds__(256) void k_csi(const float* __restrict__ ws,
                                             const float* __restrict__ freq,
                                             float* __restrict__ out) {
    const int bb = blockIdx.x;
    const int t  = threadIdx.x;

    __shared__ float Ms[64 * 68];   // ~17 KiB
    __shared__ float Fs[64 * 65];   // ~16.6 KiB
    __shared__ float red[4][64];

    const float4* M4 = (const float4*)(ws + WS_MSUM);
#pragma unroll
    for (int i = 0; i < 4; ++i) {
        const int idx4 = i * 256 + t;
        const float4 s = M4[idx4];
        const int r = idx4 >> 4, c4 = idx4 & 15;
        *(float4*)&Ms[r * 68 + c4 * 4] = s;
    }

    const float4* F4 = (const float4*)freq + bb * 1024;
#pragma unroll
    for (int i = 0; i < 4; ++i) {
        const int idx4 = i * 256 + t;
        const float4 v = F4[idx4];
        const int row = idx4 >> 4, c4 = idx4 & 15;
        Fs[row * 65 + c4 * 4 + 0] = v.x;
        Fs[row * 65 + c4 * 4 + 1] = v.y;
        Fs[row * 65 + c4 * 4 + 2] = v.z;
        Fs[row * 65 + c4 * 4 + 3] = v.w;
    }
    __syncthreads();

    const int kl = t & 63;
    const int jg = t >> 6;

    float h[16];
#pragma unroll
    for (int j = 0; j < 16; ++j) h[j] = 0.f;

    for (int r = 0; r < 64; ++r) {
        const float fv = Fs[kl * 65 + r];
        const float4* mr = (const float4*)&Ms[r * 68 + jg * 16];
        const float4 m0 = mr[0], m1 = mr[1], m2 = mr[2], m3 = mr[3];
        h[0]  += fv * m0.x; h[1]  += fv * m0.y; h[2]  += fv * m0.z; h[3]  += fv * m0.w;
        h[4]  += fv * m1.x; h[5]  += fv * m1.y; h[6]  += fv * m1.z; h[7]  += fv * m1.w;
        h[8]  += fv * m2.x; h[9]  += fv * m2.y; h[10] += fv * m2.z; h[11] += fv * m2.w;
        h[12] += fv * m3.x; h[13] += fv * m3.y; h[14] += fv * m3.z; h[15] += fv * m3.w;
    }

    float part = 0.f;
#pragma unroll
    for (int j = 0; j < 16; ++j) part += h[j] * Fs[kl * 65 + jg * 16 + j];

    red[jg][kl] = part;
    __syncthreads();
    if (t < 64) {
        out[bb * 64 + t] =
            (red[0][t] + red[1][t] + red[2][t] + red[3][t]) * (1.0f / (float)D_DIRS);
    }
}

extern "C" void kernel_launch(void* const* d_in, const int* in_sizes, int n_in,
                              void* d_out, int out_size, void* d_ws, size_t ws_size,
                              hipStream_t stream) {
    const float* atten = (const float*)d_in[0]; // (D,P,R)
    const float* rad   = (const float*)d_in[1]; // (D,P,R)
    const float* freq  = (const float*)d_in[2]; // (K,R)
    float* out = (float*)d_out;                 // (K,)
    float* ws  = (float*)d_ws;                  // needs 1.5 MiB

    k_reduce_p<<<D_DIRS / 4, 512, 0, stream>>>(atten, rad, ws);
    k_partial_m<<<NB_B, 256, 0, stream>>>(ws);
    k_reduce_m<<<4, 256, 0, stream>>>(ws);
    k_csi<<<16, 256, 0, stream>>>(ws, freq, out);
}

// Round 7
// 148.880 us; speedup vs baseline: 1.0650x; 1.0650x over previous
//
#include <hip/hip_runtime.h>

// Problem constants (fixed by reference)
#define D_DIRS 1024
#define P_PTS  256
#define R_RANK 64
#define K_SUB  1024

typedef float v4f __attribute__((ext_vector_type(4)));

// Workspace layout in floats:
//   a[D][R]      @ 0        (65536)
//   b[D][R]      @ 65536    (65536)
//   Msum[64][64] @ 131072   (4096)   -- zeroed by k1 block 0, atomically
//                                       accumulated by k_partial_m.
#define WS_A 0
#define WS_B (D_DIRS * R_RANK)
#define WS_MSUM (2 * D_DIRS * R_RANK)
#define NB_B 32
#define DCHUNK (D_DIRS / NB_B) // 32

__device__ __forceinline__ v4f ntload(const v4f* __restrict__ p) {
    return __builtin_nontemporal_load(p);
}

__device__ __forceinline__ v4f shfl_xor_v4(v4f v, int m) {
    v4f r;
    r.x = __shfl_xor(v.x, m);
    r.y = __shfl_xor(v.y, m);
    r.z = __shfl_xor(v.z, m);
    r.w = __shfl_xor(v.w, m);
    return r;
}

// ---------------------------------------------------------------------------
// Kernel 1: p-reduction.  a[d,r] = sum_p atten[d,p,r]; b likewise.
// R5 structure verbatim (best measured: ~33 us, ~4.1 TB/s read — the highest
// read-only rate observed on this part across 6 structural variants; R6's
// global_load_lds DMA path was SLOWER at 3.1 TB/s). Barrier-free wave-private
// streaming: wave owns (d, half-slab); 2-deep 8-load-chunk pipeline keeps 16
// NT loads in flight; reduction via 3 in-register shfl_xor rounds; no LDS.
// Addition for R7: block 0 lanes zero-init Msum (harness poisons ws with
// 0xAA; k_partial_m atomically accumulates into it — kernel boundary orders
// the zeroing before any atomic).
// ---------------------------------------------------------------------------
__global__ __launch_bounds__(512) void k_reduce_p(const float* __restrict__ atten,
                                                  const float* __restrict__ rad,
                                                  float* __restrict__ ws) {
    const int t    = threadIdx.x;
    const int wave = t >> 6;
    const int lane = t & 63;
    const int d    = blockIdx.x * 4 + (wave >> 1);
    const int half = wave & 1;
    const int r4g  = lane & 7;
    const int pr   = lane >> 3;

    if (blockIdx.x == 0) { // zero Msum: 512 threads x 2 float4 = 4096 floats
        v4f z = {0.f, 0.f, 0.f, 0.f};
        ((v4f*)(ws + WS_MSUM))[t]       = z;
        ((v4f*)(ws + WS_MSUM))[t + 512] = z;
    }

    const int base = pr * 16 + half * 8 + r4g; // within-slab float4 offset, c=0
    const v4f* A4 = (const v4f*)atten + (size_t)d * 4096 + base;
    const v4f* B4 = (const v4f*)rad   + (size_t)d * 4096 + base;

    v4f pa[8], pb[8], na[8], nb[8];
#pragma unroll
    for (int j = 0; j < 8; ++j) pa[j] = ntload(A4 + j * 128);
#pragma unroll
    for (int j = 0; j < 8; ++j) pb[j] = ntload(B4 + j * 128);

    v4f acc_a = {0.f, 0.f, 0.f, 0.f};
    v4f acc_b = {0.f, 0.f, 0.f, 0.f};

#pragma unroll
    for (int mc = 0; mc < 4; ++mc) {
        if (mc < 3) {
            const int off = (mc + 1) * 8 * 128;
#pragma unroll
            for (int j = 0; j < 8; ++j) na[j] = ntload(A4 + off + j * 128);
#pragma unroll
            for (int j = 0; j < 8; ++j) nb[j] = ntload(B4 + off + j * 128);
        }
        acc_a = acc_a + (((pa[0] + pa[1]) + (pa[2] + pa[3])) +
                         ((pa[4] + pa[5]) + (pa[6] + pa[7])));
        acc_b = acc_b + (((pb[0] + pb[1]) + (pb[2] + pb[3])) +
                         ((pb[4] + pb[5]) + (pb[6] + pb[7])));
#pragma unroll
        for (int j = 0; j < 8; ++j) { pa[j] = na[j]; pb[j] = nb[j]; }
    }

    // Reduce across pr (lanes sharing r4g): xor 8, 16, 32. No barriers.
    acc_a = acc_a + shfl_xor_v4(acc_a, 8);
    acc_a = acc_a + shfl_xor_v4(acc_a, 16);
    acc_a = acc_a + shfl_xor_v4(acc_a, 32);
    acc_b = acc_b + shfl_xor_v4(acc_b, 8);
    acc_b = acc_b + shfl_xor_v4(acc_b, 16);
    acc_b = acc_b + shfl_xor_v4(acc_b, 32);

    if (pr == 0) { // lanes 0..7
        ((v4f*)(ws + WS_A))[d * 16 + half * 8 + r4g] = acc_a;
        ((v4f*)(ws + WS_B))[d * 16 + half * 8 + r4g] = acc_b;
    }
}

// ---------------------------------------------------------------------------
// Kernel 2: M accumulation.  Block bb covers d in [bb*32, bb*32+32); computes
// its 64x64 partial in registers then atomicAdds into Msum (32-way contention
// per address — 131K atomics total, negligible; fp32 reassociation is well
// inside the absmax threshold: we sit at 1.0 vs 37.8).
// ---------------------------------------------------------------------------
__global__ __launch_bounds__(256) void k_partial_m(float* __restrict__ ws) {
    const int bb = blockIdx.x;
    const int t  = threadIdx.x;

    __shared__ float sa[DCHUNK * R_RANK]; // 8 KiB
    __shared__ float sb[DCHUNK * R_RANK]; // 8 KiB

    const float4* a4 = (const float4*)(ws + WS_A) + bb * (DCHUNK * R_RANK / 4);
    const float4* b4 = (const float4*)(ws + WS_B) + bb * (DCHUNK * R_RANK / 4);
    float4* sa4 = (float4*)sa;
    float4* sb4 = (float4*)sb;
    sa4[t]       = a4[t];
    sa4[t + 256] = a4[t + 256];
    sb4[t]       = b4[t];
    sb4[t + 256] = b4[t + 256];
    __syncthreads();

    const int c  = t & 63;
    const int wg = t >> 6;

    float acc[16];
#pragma unroll
    for (int i = 0; i < 16; ++i) acc[i] = 0.f;

    for (int dd = 0; dd < DCHUNK; ++dd) {
        const float bv = sb[dd * 64 + c];
        const float4* ar = (const float4*)&sa[dd * 64 + wg * 16];
        const float4 a0 = ar[0], a1 = ar[1], a2 = ar[2], a3 = ar[3];
        acc[0]  += a0.x * bv; acc[1]  += a0.y * bv; acc[2]  += a0.z * bv; acc[3]  += a0.w * bv;
        acc[4]  += a1.x * bv; acc[5]  += a1.y * bv; acc[6]  += a1.z * bv; acc[7]  += a1.w * bv;
        acc[8]  += a2.x * bv; acc[9]  += a2.y * bv; acc[10] += a2.z * bv; acc[11] += a2.w * bv;
        acc[12] += a3.x * bv; acc[13] += a3.y * bv; acc[14] += a3.z * bv; acc[15] += a3.w * bv;
    }

    float* Msum = ws + WS_MSUM;
#pragma unroll
    for (int i = 0; i < 16; ++i)
        atomicAdd(&Msum[(wg * 16 + i) * 64 + c], acc[i]);
}

// ---------------------------------------------------------------------------
// Kernel 3: csi[k] = (1/D) F[k] Msum F[k]^T.
// 16 blocks x 256 threads; block bb owns k in [bb*64, bb*64+64).
// Fs padded stride 65 -> conflict-free; Ms reads are wave-uniform broadcasts.
// ---------------------------------------------------------------------------
__global__ __launch_bounds__(256) void k_csi(const float* __restrict__ ws,
                                             const float* __restrict__ freq,
                                             float* __restrict__ out) {
    const int bb = blockIdx.x;
    const int t  = threadIdx.x;

    __shared__ float Ms[64 * 68];   // ~17 KiB
    __shared__ float Fs[64 * 65];   // ~16.6 KiB
    __shared__ float red[4][64];

    const float4* M4 = (const float4*)(ws + WS_MSUM);
#pragma unroll
    for (int i = 0; i < 4; ++i) {
        const int idx4 = i * 256 + t;
        const float4 s = M4[idx4];
        const int r = idx4 >> 4, c4 = idx4 & 15;
        *(float4*)&Ms[r * 68 + c4 * 4] = s;
    }

    const float4* F4 = (const float4*)freq + bb * 1024;
#pragma unroll
    for (int i = 0; i < 4; ++i) {
        const int idx4 = i * 256 + t;
        const float4 v = F4[idx4];
        const int row = idx4 >> 4, c4 = idx4 & 15;
        Fs[row * 65 + c4 * 4 + 0] = v.x;
        Fs[row * 65 + c4 * 4 + 1] = v.y;
        Fs[row * 65 + c4 * 4 + 2] = v.z;
        Fs[row * 65 + c4 * 4 + 3] = v.w;
    }
    __syncthreads();

    const int kl = t & 63;
    const int jg = t >> 6;

    float h[16];
#pragma unroll
    for (int j = 0; j < 16; ++j) h[j] = 0.f;

    for (int r = 0; r < 64; ++r) {
        const float fv = Fs[kl * 65 + r];
        const float4* mr = (const float4*)&Ms[r * 68 + jg * 16];
        const float4 m0 = mr[0], m1 = mr[1], m2 = mr[2], m3 = mr[3];
        h[0]  += fv * m0.x; h[1]  += fv * m0.y; h[2]  += fv * m0.z; h[3]  += fv * m0.w;
        h[4]  += fv * m1.x; h[5]  += fv * m1.y; h[6]  += fv * m1.z; h[7]  += fv * m1.w;
        h[8]  += fv * m2.x; h[9]  += fv * m2.y; h[10] += fv * m2.z; h[11] += fv * m2.w;
        h[12] += fv * m3.x; h[13] += fv * m3.y; h[14] += fv * m3.z; h[15] += fv * m3.w;
    }

    float part = 0.f;
#pragma unroll
    for (int j = 0; j < 16; ++j) part += h[j] * Fs[kl * 65 + jg * 16 + j];

    red[jg][kl] = part;
    __syncthreads();
    if (t < 64) {
        out[bb * 64 + t] =
            (red[0][t] + red[1][t] + red[2][t] + red[3][t]) * (1.0f / (float)D_DIRS);
    }
}

extern "C" void kernel_launch(void* const* d_in, const int* in_sizes, int n_in,
                              void* d_out, int out_size, void* d_ws, size_t ws_size,
                              hipStream_t stream) {
    const float* atten = (const float*)d_in[0]; // (D,P,R)
    const float* rad   = (const float*)d_in[1]; // (D,P,R)
    const float* freq  = (const float*)d_in[2]; // (K,R)
    float* out = (float*)d_out;                 // (K,)
    float* ws  = (float*)d_ws;                  // needs 528 KiB

    k_reduce_p<<<D_DIRS / 4, 512, 0, stream>>>(atten, rad, ws);
    k_partial_m<<<NB_B, 256, 0, stream>>>(ws);
    k_csi<<<16, 256, 0, stream>>>(ws, freq, out);
}